// Round 6
// baseline (4344.714 us; speedup 1.0000x reference)
//
#include <hip/hip_runtime.h>

// 2-layer GRU, B=512 T=2048 IN=16 H=128 OUT=8.
// 32 WGs x 256 threads (4 waves, 1 wave/SIMD -> 512-reg budget).
// Wave w owns hidden rows [32w,32w+32) (2 MFMA tiles) of both layers.
// Transposed MFMA: A=weights, B=h/x, D rows=hidden, cols=batch.
// Merged tick (one barrier): tick t computes h0(t) + h1(t-1) from one read
// of h0(t-1). B-frags shared across the wave's 2 tiles => half the LDS
// traffic of the 8-wave design. ALL biases folded into MFMA via constant-1
// slot at k=16 of the x-operand (no bias regs, no bias LDS, no acc init).

typedef unsigned int  uint;
typedef unsigned short ushort;
typedef _Float16 v8h __attribute__((ext_vector_type(8)));
typedef float    v4f __attribute__((ext_vector_type(4)));
typedef uint     v2u __attribute__((ext_vector_type(2)));

#define Tq   2048
#define INq  16
#define Hq   128
#define OUTq 8

#define MFMA(a,b,c) __builtin_amdgcn_mfma_f32_16x16x32_f16((a),(b),(c),0,0,0)
#define BAR() do { asm volatile("s_waitcnt lgkmcnt(0)" ::: "memory"); \
                   __builtin_amdgcn_s_barrier(); \
                   asm volatile("" ::: "memory"); } while(0)

__device__ __forceinline__ float sigm(float x){
  return __builtin_amdgcn_rcpf(1.0f + __expf(-x));
}
__device__ __forceinline__ float tanh_f(float x){
  return 1.0f - 2.0f*__builtin_amdgcn_rcpf(__expf(2.0f*x) + 1.0f);
}
__device__ __forceinline__ uint packh2(float lo, float hi){
  _Float16 a=(_Float16)lo, b=(_Float16)hi;
  return (uint)__builtin_bit_cast(ushort,a) | ((uint)__builtin_bit_cast(ushort,b)<<16);
}

__global__ __launch_bounds__(256,1) void gru2_kernel(
    const float* __restrict__ x,
    const float* __restrict__ Wih0, const float* __restrict__ Whh0,
    const float* __restrict__ bih0, const float* __restrict__ bhh0,
    const float* __restrict__ Wih1, const float* __restrict__ Whh1,
    const float* __restrict__ bih1, const float* __restrict__ bhh1,
    const float* __restrict__ Wout, const float* __restrict__ bout,
    float* __restrict__ out)
{
  const int tid  = threadIdx.x;
  const int lane = tid & 63;
  const int w    = tid >> 6;        // wave 0..3: hidden rows [32w,32w+32)
  const int nb   = lane & 15;       // batch col (B/D col); A-row select
  const int bg   = lane >> 4;       // k-group; D row-group
  const int b0   = blockIdx.x * 16;

  __shared__ __align__(16) _Float16 hA0[2][2048];  // [buf][nb*128+(c^nb)*8+e]
  __shared__ __align__(16) _Float16 hA1[2][2048];
  for (int i=tid; i<2048; i+=256){ ((uint*)hA0)[i]=0u; ((uint*)hA1)[i]=0u; }

  // x prefetch, 1-deep: xfa/xfb hold x(t) at top of tick t
  const float* xrow = x + (size_t)(b0+nb)*Tq*INq;
  float4 xfa, xfb;
  if (bg < 2){
    xfa = *(const float4*)(xrow + bg*8);
    xfb = *(const float4*)(xrow + bg*8 + 4);
  }

  // -------- weights as f16 A-fragments (2 tiles per wave) --------
  // Fx carries L0 r/z/nx bias in k=16 column; Fb[ta][q] = sparse bias frags
  // for q: 0=L0 nh, 1=L1 r, 2=L1 z, 3=L1 nx, 4=L1 nh.
  v8h Fhh0[2][3][4], Fih1[2][3][4], Fhh1[2][3][4], Fx[2][3], Fb[2][5], Fo[4];
  #pragma unroll
  for (int ta=0; ta<2; ++ta){
    const int R = 32*w + 16*ta + nb;           // A-row (hidden) this lane holds
    #pragma unroll
    for (int g=0; g<3; ++g){
      const int r = g*Hq + R;
      #pragma unroll
      for (int ks=0; ks<4; ++ks){
        const float* p0 = &Whh0[r*Hq + ks*32 + bg*8];
        const float* p1 = &Wih1[r*Hq + ks*32 + bg*8];
        const float* p2 = &Whh1[r*Hq + ks*32 + bg*8];
        v8h a, b, c;
        #pragma unroll
        for (int e=0;e<8;++e){ a[e]=(_Float16)p0[e]; b[e]=(_Float16)p1[e]; c[e]=(_Float16)p2[e]; }
        Fhh0[ta][g][ks]=a; Fih1[ta][g][ks]=b; Fhh1[ta][g][ks]=c;
      }
      v8h vx;
      #pragma unroll
      for (int e=0;e<8;++e) vx[e]=(_Float16)0.f;
      if (bg < 2){
        const float* p = &Wih0[r*INq + bg*8];
        #pragma unroll
        for (int e=0;e<8;++e) vx[e]=(_Float16)p[e];
      }
      if (bg == 2){                            // bias in k=16 column
        float bv = (g==0) ? (bih0[R]      + bhh0[R])
                 : (g==1) ? (bih0[Hq+R]   + bhh0[Hq+R])
                 :          (bih0[2*Hq+R]);
        vx[0] = (_Float16)bv;
      }
      Fx[ta][g]=vx;
    }
    #pragma unroll
    for (int q=0; q<5; ++q){
      v8h v;
      #pragma unroll
      for (int e=0;e<8;++e) v[e]=(_Float16)0.f;
      if (bg == 2){
        float bv = (q==0) ? bhh0[2*Hq+R]
                 : (q==1) ? (bih1[R]      + bhh1[R])
                 : (q==2) ? (bih1[Hq+R]   + bhh1[Hq+R])
                 : (q==3) ? bih1[2*Hq+R]
                 :          bhh1[2*Hq+R];
        v[0] = (_Float16)bv;
      }
      Fb[ta][q]=v;
    }
  }
  #pragma unroll
  for (int ks=0; ks<4; ++ks){
    v8h v;
    #pragma unroll
    for (int e=0;e<8;++e) v[e]=(_Float16)0.f;
    if (nb < OUTq){
      const float* p = &Wout[nb*Hq + ks*32 + bg*8];
      #pragma unroll
      for (int e=0;e<8;++e) v[e]=(_Float16)p[e];
    }
    Fo[ks]=v;
  }
  v4f bo4 = {0.f,0.f,0.f,0.f};
  if (bg < 2) bo4 = *(const v4f*)(bout + bg*4);
  const v4f zf = {0.f,0.f,0.f,0.f};

  float h0s[2][4] = {{0,0,0,0},{0,0,0,0}};   // h-state, D layout, per tile
  float h1s[2][4] = {{0,0,0,0},{0,0,0,0}};

  int rb[4];
  #pragma unroll
  for (int ks=0; ks<4; ++ks) rb[ks] = nb*128 + ((ks*4+bg) ^ nb)*8;
  const int wof0 = nb*128 + (((4*w + 0 + (bg>>1)) ^ nb))*8 + (bg&1)*4;
  const int wof1 = nb*128 + (((4*w + 2 + (bg>>1)) ^ nb))*8 + (bg&1)*4;

  __syncthreads();

// tick T_: compute h0(T_) [DOH0] and h1(T_-1) [DOH1]; store out(T_-2).
// Reads hA0[CUR^1]=h0(T_-1), hA1[CUR]=h1(T_-2); writes hA0[CUR], hA1[CUR^1].
#define TICK(T_, CUR, DOH0, DOH1) do {                                        \
  v8h a0k[4], a1k[4];                                                         \
  if (DOH1){                                                                  \
    _Pragma("unroll")                                                         \
    for (int ks=0;ks<4;++ks) a0k[ks] = *(const v8h*)&hA0[(CUR)^1][rb[ks]];    \
    _Pragma("unroll")                                                         \
    for (int ks=0;ks<4;++ks) a1k[ks] = *(const v8h*)&hA1[(CUR)][rb[ks]];      \
  }                                                                           \
  v8h ax;                                                                     \
  _Pragma("unroll")                                                           \
  for (int e=0;e<8;++e) ax[e]=(_Float16)0.f;                                  \
  if (bg == 2) ax[0]=(_Float16)1.0f;                                          \
  if ((DOH0) && bg < 2){                                                      \
    ax[0]=(_Float16)xfa.x; ax[1]=(_Float16)xfa.y;                             \
    ax[2]=(_Float16)xfa.z; ax[3]=(_Float16)xfa.w;                             \
    ax[4]=(_Float16)xfb.x; ax[5]=(_Float16)xfb.y;                             \
    ax[6]=(_Float16)xfb.z; ax[7]=(_Float16)xfb.w;                             \
    int tn = (T_)+1; if (tn > Tq-1) tn = Tq-1;                                \
    xfa = *(const float4*)(xrow + tn*INq + bg*8);                             \
    xfb = *(const float4*)(xrow + tn*INq + bg*8 + 4);                         \
  }                                                                           \
  if (DOH0){                                                                  \
    _Pragma("unroll")                                                         \
    for (int ta=0; ta<2; ++ta){                                               \
      v4f aR  = MFMA(Fx[ta][0], ax, zf);                                      \
      v4f aZ  = MFMA(Fx[ta][1], ax, zf);                                      \
      v4f aNX = MFMA(Fx[ta][2], ax, zf);                                      \
      v4f aNH = MFMA(Fb[ta][0], ax, zf);                                      \
      if (DOH1){                                                              \
        _Pragma("unroll")                                                     \
        for (int ks=0;ks<4;++ks){                                             \
          aR  = MFMA(Fhh0[ta][0][ks], a0k[ks], aR);                           \
          aZ  = MFMA(Fhh0[ta][1][ks], a0k[ks], aZ);                           \
          aNH = MFMA(Fhh0[ta][2][ks], a0k[ks], aNH);                          \
        }                                                                     \
      }                                                                       \
      float hn[4];                                                            \
      _Pragma("unroll")                                                       \
      for (int j=0;j<4;++j){                                                  \
        float r = sigm(aR[j]);                                                \
        float z = sigm(aZ[j]);                                                \
        float n = tanh_f(aNX[j] + r*aNH[j]);                                  \
        float h = n + z*(h0s[ta][j]-n);                                       \
        h0s[ta][j]=h; hn[j]=h;                                                \
      }                                                                       \
      v2u pk; pk[0]=packh2(hn[0],hn[1]); pk[1]=packh2(hn[2],hn[3]);           \
      *(v2u*)&hA0[(CUR)][ta ? wof1 : wof0] = pk;                              \
    }                                                                         \
  }                                                                           \
  if (DOH1){                                                                  \
    _Pragma("unroll")                                                         \
    for (int ta=0; ta<2; ++ta){                                               \
      v4f cR  = MFMA(Fb[ta][1], ax, zf);                                      \
      v4f cZ  = MFMA(Fb[ta][2], ax, zf);                                      \
      v4f cNX = MFMA(Fb[ta][3], ax, zf);                                      \
      v4f cNH = MFMA(Fb[ta][4], ax, zf);                                      \
      _Pragma("unroll")                                                       \
      for (int ks=0;ks<4;++ks){                                               \
        cR  = MFMA(Fih1[ta][0][ks], a0k[ks], cR);                             \
        cZ  = MFMA(Fih1[ta][1][ks], a0k[ks], cZ);                             \
        cNX = MFMA(Fih1[ta][2][ks], a0k[ks], cNX);                            \
        cR  = MFMA(Fhh1[ta][0][ks], a1k[ks], cR);                             \
        cZ  = MFMA(Fhh1[ta][1][ks], a1k[ks], cZ);                             \
        cNH = MFMA(Fhh1[ta][2][ks], a1k[ks], cNH);                            \
      }                                                                       \
      float hn[4];                                                            \
      _Pragma("unroll")                                                       \
      for (int j=0;j<4;++j){                                                  \
        float r = sigm(cR[j]);                                                \
        float z = sigm(cZ[j]);                                                \
        float n = tanh_f(cNX[j] + r*cNH[j]);                                  \
        float h = n + z*(h1s[ta][j]-n);                                       \
        h1s[ta][j]=h; hn[j]=h;                                                \
      }                                                                       \
      v2u pk; pk[0]=packh2(hn[0],hn[1]); pk[1]=packh2(hn[2],hn[3]);           \
      *(v2u*)&hA1[(CUR)^1][ta ? wof1 : wof0] = pk;                            \
    }                                                                         \
    if (w == 3){                                                              \
      v4f oac = zf;                                                           \
      _Pragma("unroll")                                                       \
      for (int ks=0;ks<4;++ks) oac = MFMA(Fo[ks], a1k[ks], oac);              \
      if (bg < 2){                                                            \
        int to = (T_) - 2; if (to < 0) to = 0;                                \
        float4 o;                                                             \
        o.x=oac[0]+bo4[0]; o.y=oac[1]+bo4[1];                                 \
        o.z=oac[2]+bo4[2]; o.w=oac[3]+bo4[3];                                 \
        *(float4*)&out[((size_t)(b0+nb)*Tq + to)*OUTq + bg*4] = o;            \
      }                                                                       \
    }                                                                         \
  }                                                                           \
  BAR();                                                                      \
} while(0)

  TICK(0, 0, true, false);                    // h0(0) only
  for (int t=1; t<Tq-1; t+=2){
    TICK(t,   1, true, true);
    TICK(t+1, 0, true, true);
  }
  TICK(Tq-1, 1, true, true);                  // t = 2047
  TICK(Tq,   0, false, true);                 // h1(2047) + out(2046)

  // epilogue: out(Tq-1) from h1(Tq-1) in hA1[1]
  if (w == 3){
    v4f oac = zf;
    #pragma unroll
    for (int ks=0; ks<4; ++ks){
      v8h a1 = *(const v8h*)&hA1[1][rb[ks]];
      oac = MFMA(Fo[ks], a1, oac);
    }
    if (bg < 2){
      float4 o;
      o.x=oac[0]+bo4[0]; o.y=oac[1]+bo4[1]; o.z=oac[2]+bo4[2]; o.w=oac[3]+bo4[3];
      *(float4*)&out[((size_t)(b0+nb)*Tq + (Tq-1))*OUTq + bg*4] = o;
    }
  }
}

extern "C" void kernel_launch(void* const* d_in, const int* in_sizes, int n_in,
                              void* d_out, int out_size, void* d_ws, size_t ws_size,
                              hipStream_t stream) {
  const float* x    = (const float*)d_in[0];
  const float* Wih0 = (const float*)d_in[1];
  const float* Whh0 = (const float*)d_in[2];
  const float* bih0 = (const float*)d_in[3];
  const float* bhh0 = (const float*)d_in[4];
  const float* Wih1 = (const float*)d_in[5];
  const float* Whh1 = (const float*)d_in[6];
  const float* bih1 = (const float*)d_in[7];
  const float* bhh1 = (const float*)d_in[8];
  const float* Wout = (const float*)d_in[9];
  const float* bo   = (const float*)d_in[10];
  gru2_kernel<<<dim3(32), dim3(256), 0, stream>>>(
      x, Wih0, Whh0, bih0, bhh0, Wih1, Whh1, bih1, bhh1, Wout, bo,
      (float*)d_out);
}

// Round 7
// 3487.571 us; speedup vs baseline: 1.2458x; 1.2458x over previous
//
#include <hip/hip_runtime.h>

// 2-layer GRU, B=512 T=2048 IN=16 H=128 OUT=8.
// 32 WGs x 512 threads (8 waves, 2/SIMD). ROLE-SPLIT ANTIPHASE:
//   waves 0-3 = layer-0 (32 hidden rows each), waves 4-7 = layer-1.
//   SIMD i hosts wave i (L0) + wave i+4 (L1): independent dep chains ->
//   HW wave arbiter hides each wave's latency under the other's issue.
// Tick t: L0 computes h0(t) from h0(t-1),x(t); L1 computes h1(t-1) from
// h0(t-1),h1(t-2); wave 3 computes out(t-2). ONE barrier per tick.
// Weights in regs as f16 A-frags, UNION arrays by role (<=256 regs/wave):
//   W1 = Whh0 (L0) | Wih1 (L1);  W2[..][0] = Wih0 (L0) | W2 = Whh1 (L1);
//   W3 = Wout (wave 3 only). Biases via LDS-table acc-init (b128 reads).
// Transposed MFMA: A=weights, B=h/x, D rows=hidden, cols=batch.

typedef unsigned int  uint;
typedef unsigned short ushort;
typedef _Float16 v8h __attribute__((ext_vector_type(8)));
typedef float    v4f __attribute__((ext_vector_type(4)));
typedef uint     v2u __attribute__((ext_vector_type(2)));

#define Tq   2048
#define INq  16
#define Hq   128
#define OUTq 8

#define MFMA(a,b,c) __builtin_amdgcn_mfma_f32_16x16x32_f16((a),(b),(c),0,0,0)
#define BAR() do { asm volatile("s_waitcnt lgkmcnt(0)" ::: "memory"); \
                   __builtin_amdgcn_s_barrier(); \
                   asm volatile("" ::: "memory"); } while(0)

__device__ __forceinline__ float sigm(float x){
  return __builtin_amdgcn_rcpf(1.0f + __expf(-x));
}
__device__ __forceinline__ float tanh_f(float x){
  return 1.0f - 2.0f*__builtin_amdgcn_rcpf(__expf(2.0f*x) + 1.0f);
}
__device__ __forceinline__ uint packh2(float lo, float hi){
  _Float16 a=(_Float16)lo, b=(_Float16)hi;
  return (uint)__builtin_bit_cast(ushort,a) | ((uint)__builtin_bit_cast(ushort,b)<<16);
}

__global__ __launch_bounds__(512,2) void gru2_kernel(
    const float* __restrict__ x,
    const float* __restrict__ Wih0, const float* __restrict__ Whh0,
    const float* __restrict__ bih0, const float* __restrict__ bhh0,
    const float* __restrict__ Wih1, const float* __restrict__ Whh1,
    const float* __restrict__ bih1, const float* __restrict__ bhh1,
    const float* __restrict__ Wout, const float* __restrict__ bout,
    float* __restrict__ out)
{
  const int tid  = threadIdx.x;
  const int lane = tid & 63;
  const int w    = tid >> 6;        // wave 0..7
  const int wl   = w & 3;           // hidden-slice index within role
  const bool isL0 = (w < 4);
  const int nb   = lane & 15;       // batch col
  const int bg   = lane >> 4;       // k-group / D row-group
  const int b0   = blockIdx.x * 16;

  __shared__ __align__(16) _Float16 hA0[2][2048];  // [buf][nb*128+(c^nb)*8+e]
  __shared__ __align__(16) _Float16 hA1[2][2048];
  __shared__ __align__(16) float    bl[1024];      // 8 x 128 bias table
  for (int i=tid; i<2048; i+=512){ ((uint*)hA0)[i]=0u; ((uint*)hA1)[i]=0u; }
  for (int i=tid; i<1024; i+=512){
    const int k=i>>7, h=i&127; float v;
    if      (k==0) v = bih0[h]       + bhh0[h];
    else if (k==1) v = bih0[128+h]   + bhh0[128+h];
    else if (k==2) v = bih0[256+h];
    else if (k==3) v = bhh0[256+h];
    else if (k==4) v = bih1[h]       + bhh1[h];
    else if (k==5) v = bih1[128+h]   + bhh1[128+h];
    else if (k==6) v = bih1[256+h];
    else           v = bhh1[256+h];
    bl[i]=v;
  }

  // x prefetch (L0 waves only), 1-deep
  const float* xrow = x + (size_t)(b0+nb)*Tq*INq;
  float4 xfa, xfb;
  if (isL0 && bg < 2){
    xfa = *(const float4*)(xrow + bg*8);
    xfb = *(const float4*)(xrow + bg*8 + 4);
  }

  // -------- weight fragments (union by role) --------
  v8h W1[2][3][4], W2[2][3][4], W3[4];
  #pragma unroll
  for (int ta=0; ta<2; ++ta){
    const int R = 32*wl + 16*ta + nb;
    #pragma unroll
    for (int g=0; g<3; ++g){
      const int r = g*Hq + R;
      #pragma unroll
      for (int ks=0; ks<4; ++ks){
        const float* p1 = isL0 ? &Whh0[r*Hq + ks*32 + bg*8]
                               : &Wih1[r*Hq + ks*32 + bg*8];
        v8h a;
        #pragma unroll
        for (int e=0;e<8;++e) a[e]=(_Float16)p1[e];
        W1[ta][g][ks]=a;
      }
      if (isL0){
        v8h vx;
        #pragma unroll
        for (int e=0;e<8;++e) vx[e]=(_Float16)0.f;
        if (bg < 2){
          const float* p = &Wih0[r*INq + bg*8];
          #pragma unroll
          for (int e=0;e<8;++e) vx[e]=(_Float16)p[e];
        }
        W2[ta][g][0]=vx;
      } else {
        #pragma unroll
        for (int ks=0; ks<4; ++ks){
          const float* p2 = &Whh1[r*Hq + ks*32 + bg*8];
          v8h c;
          #pragma unroll
          for (int e=0;e<8;++e) c[e]=(_Float16)p2[e];
          W2[ta][ks==0?g:g][ks]=c;   // W2[ta][g][ks]
        }
      }
    }
  }
  if (w == 3){
    #pragma unroll
    for (int ks=0; ks<4; ++ks){
      v8h v;
      #pragma unroll
      for (int e=0;e<8;++e) v[e]=(_Float16)0.f;
      if (nb < OUTq){
        const float* p = &Wout[nb*Hq + ks*32 + bg*8];
        #pragma unroll
        for (int e=0;e<8;++e) v[e]=(_Float16)p[e];
      }
      W3[ks]=v;
    }
  }
  v4f bo4 = {0.f,0.f,0.f,0.f};
  if (bg < 2) bo4 = *(const v4f*)(bout + bg*4);
  const v4f zf = {0.f,0.f,0.f,0.f};

  float hs[2][4] = {{0,0,0,0},{0,0,0,0}};   // h0 (L0 waves) or h1 (L1 waves)

  int rb[4];
  #pragma unroll
  for (int ks=0; ks<4; ++ks) rb[ks] = nb*128 + ((ks*4+bg) ^ nb)*8;
  const int wof0 = nb*128 + (((4*wl + 0 + (bg>>1)) ^ nb))*8 + (bg&1)*4;
  const int wof1 = nb*128 + (((4*wl + 2 + (bg>>1)) ^ nb))*8 + (bg&1)*4;

  __syncthreads();

  for (int t=0; t<=Tq; ++t){
    const int pb = (t+1)&1;           // buffer holding h0(t-1) / receives h1(t-1)
    const int cb = t&1;               // receives h0(t); holds h1(t-2)

    if (isL0){
      if (t < Tq){
        v8h ax;
        #pragma unroll
        for (int e=0;e<8;++e) ax[e]=(_Float16)0.f;
        if (bg < 2){
          ax[0]=(_Float16)xfa.x; ax[1]=(_Float16)xfa.y; ax[2]=(_Float16)xfa.z; ax[3]=(_Float16)xfa.w;
          ax[4]=(_Float16)xfb.x; ax[5]=(_Float16)xfb.y; ax[6]=(_Float16)xfb.z; ax[7]=(_Float16)xfb.w;
          int tn = t+1; if (tn > Tq-1) tn = Tq-1;
          xfa = *(const float4*)(xrow + tn*INq + bg*8);
          xfb = *(const float4*)(xrow + tn*INq + bg*8 + 4);
        }
        v8h a0k[4];
        #pragma unroll
        for (int ks=0; ks<4; ++ks) a0k[ks] = *(const v8h*)&hA0[pb][rb[ks]];
        #pragma unroll
        for (int ta=0; ta<2; ++ta){
          const int hb4 = 32*wl + 16*ta + bg*4;
          v4f aR  = *(const v4f*)&bl[0*128+hb4];
          v4f aZ  = *(const v4f*)&bl[1*128+hb4];
          v4f aNX = *(const v4f*)&bl[2*128+hb4];
          v4f aNH = *(const v4f*)&bl[3*128+hb4];
          aR  = MFMA(W2[ta][0][0], ax, aR);
          aZ  = MFMA(W2[ta][1][0], ax, aZ);
          aNX = MFMA(W2[ta][2][0], ax, aNX);
          #pragma unroll
          for (int ks=0; ks<4; ++ks){
            aR  = MFMA(W1[ta][0][ks], a0k[ks], aR);
            aZ  = MFMA(W1[ta][1][ks], a0k[ks], aZ);
            aNH = MFMA(W1[ta][2][ks], a0k[ks], aNH);
          }
          float hn[4];
          #pragma unroll
          for (int j=0;j<4;++j){
            float r = sigm(aR[j]);
            float z = sigm(aZ[j]);
            float n = tanh_f(aNX[j] + r*aNH[j]);
            float h = n + z*(hs[ta][j]-n);
            hs[ta][j]=h; hn[j]=h;
          }
          v2u pk; pk[0]=packh2(hn[0],hn[1]); pk[1]=packh2(hn[2],hn[3]);
          *(v2u*)&hA0[cb][ta ? wof1 : wof0] = pk;
        }
      }
      if (w == 3 && t >= 1){          // out(t-2) from h1(t-2) in hA1[cb]
        v4f oac = zf;
        #pragma unroll
        for (int ks=0; ks<4; ++ks){
          v8h a1 = *(const v8h*)&hA1[cb][rb[ks]];
          oac = MFMA(W3[ks], a1, oac);
        }
        if (t >= 2 && bg < 2){
          float4 o;
          o.x=oac[0]+bo4[0]; o.y=oac[1]+bo4[1]; o.z=oac[2]+bo4[2]; o.w=oac[3]+bo4[3];
          *(float4*)&out[((size_t)(b0+nb)*Tq + (t-2))*OUTq + bg*4] = o;
        }
      }
    } else if (t >= 1){               // L1: h1(t-1)
      v8h a0k[4];
      #pragma unroll
      for (int ks=0; ks<4; ++ks) a0k[ks] = *(const v8h*)&hA0[pb][rb[ks]];
      #pragma unroll
      for (int ta=0; ta<2; ++ta){
        const int hb4 = 32*wl + 16*ta + bg*4;
        v4f cR  = *(const v4f*)&bl[4*128+hb4];
        v4f cZ  = *(const v4f*)&bl[5*128+hb4];
        v4f cNX = *(const v4f*)&bl[6*128+hb4];
        v4f cNH = *(const v4f*)&bl[7*128+hb4];
        #pragma unroll
        for (int ks=0; ks<4; ++ks){
          v8h a1 = *(const v8h*)&hA1[cb][rb[ks]];
          cR  = MFMA(W1[ta][0][ks], a0k[ks], cR);
          cZ  = MFMA(W1[ta][1][ks], a0k[ks], cZ);
          cNX = MFMA(W1[ta][2][ks], a0k[ks], cNX);
          cR  = MFMA(W2[ta][0][ks], a1, cR);
          cZ  = MFMA(W2[ta][1][ks], a1, cZ);
          cNH = MFMA(W2[ta][2][ks], a1, cNH);
        }
        float hn[4];
        #pragma unroll
        for (int j=0;j<4;++j){
          float r = sigm(cR[j]);
          float z = sigm(cZ[j]);
          float n = tanh_f(cNX[j] + r*cNH[j]);
          float h = n + z*(hs[ta][j]-n);
          hs[ta][j]=h; hn[j]=h;
        }
        v2u pk; pk[0]=packh2(hn[0],hn[1]); pk[1]=packh2(hn[2],hn[3]);
        *(v2u*)&hA1[pb][ta ? wof1 : wof0] = pk;
      }
    }
    BAR();
  }

  // epilogue: out(Tq-1) from h1(Tq-1) in hA1[1]
  if (w == 3){
    v4f oac = zf;
    #pragma unroll
    for (int ks=0; ks<4; ++ks){
      v8h a1 = *(const v8h*)&hA1[1][rb[ks]];
      oac = MFMA(W3[ks], a1, oac);
    }
    if (bg < 2){
      float4 o;
      o.x=oac[0]+bo4[0]; o.y=oac[1]+bo4[1]; o.z=oac[2]+bo4[2]; o.w=oac[3]+bo4[3];
      *(float4*)&out[((size_t)(b0+nb)*Tq + (Tq-1))*OUTq + bg*4] = o;
    }
  }
}

extern "C" void kernel_launch(void* const* d_in, const int* in_sizes, int n_in,
                              void* d_out, int out_size, void* d_ws, size_t ws_size,
                              hipStream_t stream) {
  const float* x    = (const float*)d_in[0];
  const float* Wih0 = (const float*)d_in[1];
  const float* Whh0 = (const float*)d_in[2];
  const float* bih0 = (const float*)d_in[3];
  const float* bhh0 = (const float*)d_in[4];
  const float* Wih1 = (const float*)d_in[5];
  const float* Whh1 = (const float*)d_in[6];
  const float* bih1 = (const float*)d_in[7];
  const float* bhh1 = (const float*)d_in[8];
  const float* Wout = (const float*)d_in[9];
  const float* bo   = (const float*)d_in[10];
  gru2_kernel<<<dim3(32), dim3(512), 0, stream>>>(
      x, Wih0, Whh0, bih0, bhh0, Wih1, Whh1, bih1, bhh1, Wout, bo,
      (float*)d_out);
}